// Round 3
// baseline (572.228 us; speedup 1.0000x reference)
//
#include <hip/hip_runtime.h>
#include <hip/hip_bf16.h>

typedef unsigned short u16;
typedef unsigned int u32;
typedef float f32x4 __attribute__((ext_vector_type(4)));
typedef __bf16 bf16x8 __attribute__((ext_vector_type(8)));

#define AS1 __attribute__((address_space(1)))
#define AS3 __attribute__((address_space(3)))

// ---- constants -------------------------------------------------------------
// M = B*T = 32768 tokens, D = 768, H = 2048
#define MTOT 32768
#define DK   768
#define HN   2048

// Octonion tables: Big[i*A+a][c*B+b] = S2[i][c] * w[J[i][c]][a][b]
__constant__ signed char J_TAB[64] = {
  0,1,2,3,4,5,6,7,
  1,0,3,2,5,4,7,6,
  2,3,0,1,6,7,4,5,
  3,2,1,0,7,6,5,4,
  4,5,6,7,0,1,2,3,
  5,4,7,6,1,0,3,2,
  6,7,4,5,2,3,0,1,
  7,6,5,4,3,2,1,0};
__constant__ signed char S_TAB[64] = {
   1, 1, 1, 1, 1, 1, 1, 1,
  -1, 1,-1, 1,-1, 1, 1,-1,
  -1, 1, 1,-1,-1,-1, 1, 1,
  -1,-1, 1, 1,-1, 1,-1, 1,
  -1, 1, 1, 1, 1,-1,-1,-1,
  -1,-1, 1,-1, 1, 1, 1,-1,
  -1,-1,-1, 1, 1,-1, 1, 1,
  -1, 1,-1,-1, 1, 1,-1, 1};

// ---- helpers ---------------------------------------------------------------
__device__ __forceinline__ u16 f2bf(float f) {  // RNE float->bf16
  u32 x = __float_as_uint(f);
  x += 0x7fffu + ((x >> 16) & 1u);
  return (u16)(x >> 16);
}

__device__ __forceinline__ void gload_lds16(const void* g, void* l) {
  // async global->LDS, 16B per lane; LDS dest = wave-uniform base + lane*16
  __builtin_amdgcn_global_load_lds((AS1 void*)(g), (AS3 void*)(l), 16, 0, 0);
}

#define VMW(N) do { __builtin_amdgcn_sched_barrier(0); \
  asm volatile("s_waitcnt vmcnt(" #N ")" ::: "memory"); \
  __builtin_amdgcn_sched_barrier(0); } while (0)
#define BAR() do { __builtin_amdgcn_sched_barrier(0); \
  __builtin_amdgcn_s_barrier(); \
  __builtin_amdgcn_sched_barrier(0); } while (0)

// Stage one 128x64 bf16 half-tile (row-major, leading dim LDK) into contiguous
// LDS. 512 threads x 2 loads of 16B. XOR swizzle: global chunk c of row r lands
// at LDS slot c^(r&7)  (pre-swizzled global source + linear LDS dest).
template <int LDK>
__device__ __forceinline__ void stage_half(const u16* __restrict__ src,
                                           u16* lds, int tid) {
#pragma unroll
  for (int f0 = 0; f0 < 1024; f0 += 512) {
    int flat = f0 + tid;
    int row = flat >> 3;
    int c = (flat & 7) ^ (row & 7);
    gload_lds16(src + row * LDK + c * 8, lds + (f0 + (tid & ~63)) * 8);
  }
}

// Stage ROWS x 64 bf16 tile with 256 threads (gemm2). Same XOR swizzle.
template <int ROWS, int LDK>
__device__ __forceinline__ void stage_tile(const u16* __restrict__ src,
                                           u16* lds, int tid) {
#pragma unroll
  for (int f0 = 0; f0 < ROWS * 8; f0 += 256) {
    int flat = f0 + tid;
    int row = flat >> 3;
    int c = (flat & 7) ^ (row & 7);
    gload_lds16(src + row * LDK + c * 8, lds + (f0 + (tid & 192)) * 8);
  }
}

// ---- gemm1 K-tile (BK=64): 4 phases, k-sliced clusters, 1-phase read-ahead --
// clusters: C0=(m-lo,k0) C1=(m-lo,k1) C2=(m-hi,k0) C3=(m-hi,k1), 16 MFMA each.
template <int LDK, bool SA, bool SB, int VM>
__device__ __forceinline__ void ktile4(
    const u16* lAp, const u16* lBp, u16* lAn, u16* lBn,
    const u16* __restrict__ aStage, const u16* __restrict__ bStage,
    int tid, int arow, int brow, int c0, int c1, f32x4 (&acc)[8][4]) {
  bf16x8 a0[4], a1[4], a2[4], a3[4], b0[4], b1[4];
  // ---- phase 0: reads C0 then C1; stage A(S+1) h0
#pragma unroll
  for (int mi = 0; mi < 4; ++mi)
    a0[mi] = *(const bf16x8*)(lAp + (arow + mi * 16) * 64 + c0);
#pragma unroll
  for (int ni = 0; ni < 4; ++ni)
    b0[ni] = *(const bf16x8*)(lBp + (brow + ni * 16) * 64 + c0);
#pragma unroll
  for (int mi = 0; mi < 4; ++mi)
    a1[mi] = *(const bf16x8*)(lAp + (arow + mi * 16) * 64 + c1);
#pragma unroll
  for (int ni = 0; ni < 4; ++ni)
    b1[ni] = *(const bf16x8*)(lBp + (brow + ni * 16) * 64 + c1);
  if constexpr (SA) stage_half<LDK>(aStage, lAn, tid);
  BAR();
  __builtin_amdgcn_s_setprio(1);
#pragma unroll
  for (int mi = 0; mi < 4; ++mi)
#pragma unroll
    for (int ni = 0; ni < 4; ++ni)
      acc[mi][ni] = __builtin_amdgcn_mfma_f32_16x16x32_bf16(
          a0[mi], b0[ni], acc[mi][ni], 0, 0, 0);
  __builtin_amdgcn_s_setprio(0);
  BAR();
  // ---- phase 1: reads C2; stage A(S+1) h1
#pragma unroll
  for (int mi = 0; mi < 4; ++mi)
    a2[mi] = *(const bf16x8*)(lAp + (arow + 64 + mi * 16) * 64 + c0);
  if constexpr (SA) stage_half<LDK>(aStage + 128 * LDK, lAn + 128 * 64, tid);
  BAR();
  __builtin_amdgcn_s_setprio(1);
#pragma unroll
  for (int mi = 0; mi < 4; ++mi)
#pragma unroll
    for (int ni = 0; ni < 4; ++ni)
      acc[mi][ni] = __builtin_amdgcn_mfma_f32_16x16x32_bf16(
          a1[mi], b1[ni], acc[mi][ni], 0, 0, 0);
  __builtin_amdgcn_s_setprio(0);
  BAR();
  // ---- phase 2: reads C3; stage B(S+2) h0
#pragma unroll
  for (int mi = 0; mi < 4; ++mi)
    a3[mi] = *(const bf16x8*)(lAp + (arow + 64 + mi * 16) * 64 + c1);
  if constexpr (SB) stage_half<LDK>(bStage, lBn, tid);
  BAR();
  __builtin_amdgcn_s_setprio(1);
#pragma unroll
  for (int mi = 0; mi < 4; ++mi)
#pragma unroll
    for (int ni = 0; ni < 4; ++ni)
      acc[4 + mi][ni] = __builtin_amdgcn_mfma_f32_16x16x32_bf16(
          a2[mi], b0[ni], acc[4 + mi][ni], 0, 0, 0);
  __builtin_amdgcn_s_setprio(0);
  BAR();
  // ---- phase 3: stage B(S+2) h1; counted vmcnt retires A(S+1)+B(S+1)
  if constexpr (SB) stage_half<LDK>(bStage + 128 * LDK, lBn + 128 * 64, tid);
  if constexpr (VM == 4) VMW(4);
  else if constexpr (VM == 0) VMW(0);
  BAR();
  __builtin_amdgcn_s_setprio(1);
#pragma unroll
  for (int mi = 0; mi < 4; ++mi)
#pragma unroll
    for (int ni = 0; ni < 4; ++ni)
      acc[4 + mi][ni] = __builtin_amdgcn_mfma_f32_16x16x32_bf16(
          a3[mi], b1[ni], acc[4 + mi][ni], 0, 0, 0);
  __builtin_amdgcn_s_setprio(0);
  BAR();
}

// ---- 256x256 pipelined GEMM core (gemm1), NK K-tiles of 64 (NK even) --------
template <int NK, int LDK>
__device__ __forceinline__ void gemm_core(const u16* __restrict__ aSrc,
                                          const u16* __restrict__ bSrc, int tid,
                                          u16* lA0, u16* lA1, u16* lB0, u16* lB1,
                                          f32x4 (&acc)[8][4]) {
  const int lane = tid & 63;
  const int wave = tid >> 6;
  const int wm = wave >> 2, wn = wave & 3;
  const int l15 = lane & 15, quad = (lane >> 4) & 3;
  const int arow = wm * 128 + l15;
  const int brow = wn * 64 + l15;
  const int c0 = (quad ^ (l15 & 7)) * 8;
  const int c1 = ((quad + 4) ^ (l15 & 7)) * 8;

  // prologue: K-tile0 (A,B) + B of K-tile1; vmcnt(4) leaves B(1) in flight
  stage_half<LDK>(aSrc, lA0, tid);
  stage_half<LDK>(aSrc + 128 * LDK, lA0 + 128 * 64, tid);
  stage_half<LDK>(bSrc, lB0, tid);
  stage_half<LDK>(bSrc + 128 * LDK, lB0 + 128 * 64, tid);
  stage_half<LDK>(bSrc + 64, lB1, tid);
  stage_half<LDK>(bSrc + 64 + 128 * LDK, lB1 + 128 * 64, tid);
  VMW(4);
  BAR();

#pragma unroll 1
  for (int i = 0; i < NK / 2 - 1; ++i) {
    ktile4<LDK, true, true, 4>(lA0, lB0, lA1, lB0,
                               aSrc + (2 * i + 1) * 64, bSrc + (2 * i + 2) * 64,
                               tid, arow, brow, c0, c1, acc);
    ktile4<LDK, true, true, 4>(lA1, lB1, lA0, lB1,
                               aSrc + (2 * i + 2) * 64, bSrc + (2 * i + 3) * 64,
                               tid, arow, brow, c0, c1, acc);
  }
  ktile4<LDK, true, false, 0>(lA0, lB0, lA1, lB0,
                              aSrc + (NK - 1) * 64, nullptr,
                              tid, arow, brow, c0, c1, acc);
  ktile4<LDK, false, false, -1>(lA1, lB1, lA0, lB1, nullptr, nullptr,
                                tid, arow, brow, c0, c1, acc);
}

// ---- prep kernels ----------------------------------------------------------
__global__ void scales1_kernel(const float* __restrict__ w0,
                               const float* __restrict__ w1,
                               const float* __restrict__ w2,
                               float* __restrict__ partials) {
  __shared__ float red[256];
  const int t = blockIdx.x / 192;      // tensor id
  const int chunk = blockIdx.x % 192;  // 1024-float chunk
  const float* w = (t == 0) ? w0 : (t == 1) ? w1 : w2;
  const float4* w4 = (const float4*)(w + chunk * 1024);
  float4 v = w4[threadIdx.x];
  red[threadIdx.x] = fabsf(v.x) + fabsf(v.y) + fabsf(v.z) + fabsf(v.w);
  __syncthreads();
  for (int off = 128; off; off >>= 1) {
    if (threadIdx.x < off) red[threadIdx.x] += red[threadIdx.x + off];
    __syncthreads();
  }
  if (threadIdx.x == 0) partials[blockIdx.x] = red[0];
}

__global__ void scales2_kernel(const float* __restrict__ partials,
                               float* __restrict__ scales) {
  __shared__ float red[256];
  float s = (threadIdx.x < 192) ? partials[blockIdx.x * 192 + threadIdx.x] : 0.f;
  red[threadIdx.x] = s;
  __syncthreads();
  for (int off = 128; off; off >>= 1) {
    if (threadIdx.x < off) red[threadIdx.x] += red[threadIdx.x + off];
    __syncthreads();
  }
  if (threadIdx.x == 0) scales[blockIdx.x] = red[0] / 196608.f + 1e-8f;
}

// Build Big^T rows ({-1,0,+1} as bf16; absmean scale folded into epilogues).
// ilv 0/1 : gate/up interleaved at 16-col granularity into B_cat [4096 x 768]
// ilv -2  : w_down with k-index permuted by phi (h physical column layout):
//           phi(k) = (k&~31) | ((k&15)<<1) | ((k>>4)&1)
__global__ void build_big_kernel(const float* __restrict__ w,
                                 const float* __restrict__ scales, int sidx,
                                 int A, int B, int ilv, u16* __restrict__ dst) {
  int idx = blockIdx.x * 256 + threadIdx.x;  // n*K8 + k, exact grid
  int K8 = 8 * A;
  int n = idx / K8;
  int k = idx - n * K8;
  int i = k / A, a = k - i * A;
  int c = n / B, b = n - c * B;
  float scale = scales[sidx];
  int j = J_TAB[i * 8 + c];
  float q = rintf(w[(j * A + a) * B + b] / scale);
  q = fminf(1.f, fmaxf(-1.f, q));
  int nd = (ilv >= 0) ? (((n & ~15) << 1) | (ilv << 4) | (n & 15)) : n;
  int kd = (ilv == -2) ? ((k & ~31) | ((k & 15) << 1) | ((k >> 4) & 1)) : k;
  dst[nd * K8 + kd] = f2bf(q * (float)S_TAB[i * 8 + c]);
}

__global__ void cvt_x_kernel(const float* __restrict__ x, u16* __restrict__ xb) {
  int gid = blockIdx.x * 256 + threadIdx.x;  // 8 floats per thread
  const float4* x4 = (const float4*)x;
  float4 v0 = x4[gid * 2], v1 = x4[gid * 2 + 1];
  uint4 o;
  o.x = (u32)f2bf(v0.x) | ((u32)f2bf(v0.y) << 16);
  o.y = (u32)f2bf(v0.z) | ((u32)f2bf(v0.w) << 16);
  o.z = (u32)f2bf(v1.x) | ((u32)f2bf(v1.y) << 16);
  o.w = (u32)f2bf(v1.z) | ((u32)f2bf(v1.w) << 16);
  ((uint4*)xb)[gid] = o;
}

// ---- GEMM1: [M x 768] @ B_cat[4096 x 768]^T -> SiLU(g)*u -> h bf16 [M x 2048]
// h columns stored permuted by phi; epilogue packs (pr0,pr1) into one u32.
__global__ __launch_bounds__(512, 2) void gemm1_kernel(
    const u16* __restrict__ xb, const u16* __restrict__ wgu,
    const float* __restrict__ scales, u16* __restrict__ h) {
  __shared__ __align__(16) u16 lA0[256 * 64], lA1[256 * 64];
  __shared__ __align__(16) u16 lB0[256 * 64], lB1[256 * 64];
  const int tid = threadIdx.x;
  const int logical = (blockIdx.x & 7) * 256 + (blockIdx.x >> 3);
  const int bn = logical & 15;   // 16 N_cat-tiles (fast: A-tile L2 reuse)
  const int bm = logical >> 4;   // 128 M-tiles
  const int m0 = bm * 256, n0 = bn * 256;

  f32x4 acc[8][4] = {};
  gemm_core<12, DK>(xb + (size_t)m0 * DK, wgu + (size_t)n0 * DK, tid,
                    lA0, lA1, lB0, lB1, acc);

  const int lane = tid & 63, wave = tid >> 6;
  const int wm = wave >> 2, wn = wave & 3;
  const int l15 = lane & 15, quad = lane >> 4;
  const float sg = scales[0], su = scales[1];
  const int a_ = bn * 4 + wn;            // 32-col physical group index
  u32* h32 = (u32*)h;
#pragma unroll
  for (int mi = 0; mi < 8; ++mi)
#pragma unroll
    for (int r = 0; r < 4; ++r) {
      int m = m0 + wm * 128 + mi * 16 + quad * 4 + r;
      float g0 = acc[mi][0][r] * sg, u0 = acc[mi][1][r] * su;
      float g1 = acc[mi][2][r] * sg, u1 = acc[mi][3][r] * su;
      float h0 = g0 / (1.f + __expf(-g0)) * u0;
      float h1 = g1 / (1.f + __expf(-g1)) * u1;
      h32[(size_t)m * (HN / 2) + a_ * 16 + l15] =
          (u32)f2bf(h0) | ((u32)f2bf(h1) << 16);
    }
}

// ---- GEMM2: [M x 2048] @ BigD -> out fp32 [M x 768] ------------------------
// 64(M) x 256(N) tile, 256 threads, 4 waves (each 64x64). Double-buffered LDS
// (80 KiB -> 2 blocks/CU co-resident: inter-block overlap hides stage stalls,
// m97 recipe). Counted vmcnt(10): stage kt S+1's 10 loads, wait only kt S's.
// Grid 1536 = 512 m-tiles x 3 n-tiles = exactly 3 rounds of 512 resident.
__global__ __launch_bounds__(256, 2) void gemm2_kernel(
    const u16* __restrict__ h, const u16* __restrict__ wd,
    const float* __restrict__ scales, float* __restrict__ out) {
  __shared__ __align__(16) u16 lA[2][64 * 64];
  __shared__ __align__(16) u16 lB[2][256 * 64];
  const int tid = threadIdx.x;
  // bijective XCD-chunked swizzle (1536 % 8 == 0); bn fastest -> the 3 sharers
  // of one h-panel are bid-adjacent (delta 8) on the same XCD.
  const int logical = (blockIdx.x & 7) * 192 + (blockIdx.x >> 3);
  const int bn = logical % 3;    // 3 N-tiles of 256
  const int bm = logical / 3;    // 512 M-tiles of 64
  const int m0 = bm * 64, n0 = bn * 256;
  const u16* aSrc = h + (size_t)m0 * HN;
  const u16* bSrc = wd + (size_t)n0 * HN;

  const int lane = tid & 63, wave = tid >> 6;
  const int l15 = lane & 15, quad = (lane >> 4) & 3;
  const int brow = wave * 64 + l15;
  const int c0 = (quad ^ (l15 & 7)) * 8;
  const int c1 = ((quad + 4) ^ (l15 & 7)) * 8;

  f32x4 acc[4][4] = {};

  // prologue: stage K-tile 0 (10 loads/thread)
  stage_tile<64, HN>(aSrc, lA[0], tid);
  stage_tile<256, HN>(bSrc, lB[0], tid);

#pragma unroll 1
  for (int S = 0; S < HN / 64; ++S) {
    if (S < HN / 64 - 1) {
      stage_tile<64, HN>(aSrc + (S + 1) * 64, lA[(S + 1) & 1], tid);
      stage_tile<256, HN>(bSrc + (S + 1) * 64, lB[(S + 1) & 1], tid);
      VMW(10);   // retire kt S's 10 loads; kt S+1's stay in flight
    } else {
      VMW(0);
    }
    BAR();
    const u16* la = lA[S & 1];
    const u16* lb = lB[S & 1];
    bf16x8 af[4][2], bf[4][2];
#pragma unroll
    for (int mi = 0; mi < 4; ++mi) {
      const u16* p = la + (l15 + mi * 16) * 64;
      af[mi][0] = *(const bf16x8*)(p + c0);
      af[mi][1] = *(const bf16x8*)(p + c1);
    }
#pragma unroll
    for (int ni = 0; ni < 4; ++ni) {
      const u16* p = lb + (brow + ni * 16) * 64;
      bf[ni][0] = *(const bf16x8*)(p + c0);
      bf[ni][1] = *(const bf16x8*)(p + c1);
    }
    __builtin_amdgcn_s_setprio(1);
#pragma unroll
    for (int k = 0; k < 2; ++k)
#pragma unroll
      for (int mi = 0; mi < 4; ++mi)
#pragma unroll
        for (int ni = 0; ni < 4; ++ni)
          acc[mi][ni] = __builtin_amdgcn_mfma_f32_16x16x32_bf16(
              af[mi][k], bf[ni][k], acc[mi][ni], 0, 0, 0);
    __builtin_amdgcn_s_setprio(0);
    BAR();
  }

  const float sd = scales[2];
#pragma unroll
  for (int mi = 0; mi < 4; ++mi)
#pragma unroll
    for (int ni = 0; ni < 4; ++ni) {
      const int n = n0 + wave * 64 + ni * 16 + l15;
#pragma unroll
      for (int r = 0; r < 4; ++r) {
        int m = m0 + mi * 16 + quad * 4 + r;
        out[(size_t)m * DK + n] = acc[mi][ni][r] * sd;
      }
    }
}

// ---- launch ----------------------------------------------------------------
extern "C" void kernel_launch(void* const* d_in, const int* in_sizes, int n_in,
                              void* d_out, int out_size, void* d_ws, size_t ws_size,
                              hipStream_t stream) {
  const float* x      = (const float*)d_in[0];
  const float* w_gate = (const float*)d_in[1];
  const float* w_up   = (const float*)d_in[2];
  const float* w_down = (const float*)d_in[3];
  float* out = (float*)d_out;

  // workspace layout (bytes):
  //  scales[3] @0 | partials[576] @256 | B_cat 6MB @4096 | BigD^T 3MB |
  //  xb 50MB | h 134MB
  char* ws = (char*)d_ws;
  float* scales   = (float*)ws;
  float* partials = (float*)(ws + 256);
  u16* wgu = (u16*)(ws + 4096);
  u16* wd  = (u16*)(ws + 4096 + 6291456u);
  u16* xb  = (u16*)(ws + 4096 + 9437184u);
  u16* h   = (u16*)(ws + 4096 + 9437184u + 50331648u);

  scales1_kernel<<<576, 256, 0, stream>>>(w_gate, w_up, w_down, partials);
  scales2_kernel<<<3, 256, 0, stream>>>(partials, scales);
  build_big_kernel<<<6144, 256, 0, stream>>>(w_gate, scales, 0, 96, 256, 0, wgu);
  build_big_kernel<<<6144, 256, 0, stream>>>(w_up,   scales, 1, 96, 256, 1, wgu);
  build_big_kernel<<<6144, 256, 0, stream>>>(w_down, scales, 2, 256, 96, -2, wd);
  cvt_x_kernel<<<12288, 256, 0, stream>>>(x, xb);
  gemm1_kernel<<<2048, 512, 0, stream>>>(xb, wgu, scales, h);
  gemm2_kernel<<<1536, 256, 0, stream>>>(h, wd, scales, out);
}

// Round 4
// 549.162 us; speedup vs baseline: 1.0420x; 1.0420x over previous
//
#include <hip/hip_runtime.h>
#include <hip/hip_bf16.h>

typedef unsigned short u16;
typedef unsigned int u32;
typedef float f32x4 __attribute__((ext_vector_type(4)));
typedef __bf16 bf16x8 __attribute__((ext_vector_type(8)));

#define AS1 __attribute__((address_space(1)))
#define AS3 __attribute__((address_space(3)))

// ---- constants -------------------------------------------------------------
// M = B*T = 32768 tokens, D = 768, H = 2048
#define MTOT 32768
#define DK   768
#define HN   2048

// Octonion tables: Big[i*A+a][c*B+b] = S2[i][c] * w[J[i][c]][a][b]
__constant__ signed char J_TAB[64] = {
  0,1,2,3,4,5,6,7,
  1,0,3,2,5,4,7,6,
  2,3,0,1,6,7,4,5,
  3,2,1,0,7,6,5,4,
  4,5,6,7,0,1,2,3,
  5,4,7,6,1,0,3,2,
  6,7,4,5,2,3,0,1,
  7,6,5,4,3,2,1,0};
__constant__ signed char S_TAB[64] = {
   1, 1, 1, 1, 1, 1, 1, 1,
  -1, 1,-1, 1,-1, 1, 1,-1,
  -1, 1, 1,-1,-1,-1, 1, 1,
  -1,-1, 1, 1,-1, 1,-1, 1,
  -1, 1, 1, 1, 1,-1,-1,-1,
  -1,-1, 1,-1, 1, 1, 1,-1,
  -1,-1,-1, 1, 1,-1, 1, 1,
  -1, 1,-1,-1, 1, 1,-1, 1};

// ---- helpers ---------------------------------------------------------------
__device__ __forceinline__ u16 f2bf(float f) {  // RNE float->bf16
  u32 x = __float_as_uint(f);
  x += 0x7fffu + ((x >> 16) & 1u);
  return (u16)(x >> 16);
}

__device__ __forceinline__ void gload_lds16(const void* g, void* l) {
  // async global->LDS, 16B per lane; LDS dest = wave-uniform base + lane*16
  __builtin_amdgcn_global_load_lds((AS1 void*)(g), (AS3 void*)(l), 16, 0, 0);
}

// R4: de-pinned. No sched_barrier(0) sandwiches (m141: order-pinning defeats
// the compiler scheduler). VMW keeps only the "memory" clobber (orders memory
// ops at the vmcnt points); BAR is a raw s_barrier. Correctness audit:
// fragment reads are compiler-visible loads (compiler inserts counted lgkm
// waits); gload_lds is a memory-writing intrinsic (no reorder vs aliasing LDS
// loads); same-buffer B staging is first-use-safe (see ktile4 comments).
#define VMW(N) asm volatile("s_waitcnt vmcnt(" #N ")" ::: "memory")
#define BAR() __builtin_amdgcn_s_barrier()

// Stage one 128x64 bf16 half-tile (row-major, leading dim LDK) into contiguous
// LDS. 512 threads x 2 loads of 16B. XOR swizzle: global chunk c of row r lands
// at LDS slot c^(r&7)  (pre-swizzled global source + linear LDS dest).
template <int LDK>
__device__ __forceinline__ void stage_half(const u16* __restrict__ src,
                                           u16* lds, int tid) {
#pragma unroll
  for (int f0 = 0; f0 < 1024; f0 += 512) {
    int flat = f0 + tid;
    int row = flat >> 3;
    int c = (flat & 7) ^ (row & 7);
    gload_lds16(src + row * LDK + c * 8, lds + (f0 + (tid & ~63)) * 8);
  }
}

// ---- gemm1 K-tile (BK=64): 4 phases, k-sliced clusters, 1-phase read-ahead --
// clusters: C0=(m-lo,k0) C1=(m-lo,k1) C2=(m-hi,k0) C3=(m-hi,k1), 16 MFMA each.
// reads: ph0: C0+C1 (16), ph1: C2 (4), ph2: C3 (4), ph3: 0. With the scheduler
// un-pinned the compiler may drain reads under the MFMA clusters (counted
// lgkmcnt) -- that interleave is the point of this round.
template <int LDK, bool SA, bool SB, int VM>
__device__ __forceinline__ void ktile4(
    const u16* lAp, const u16* lBp, u16* lAn, u16* lBn,
    const u16* __restrict__ aStage, const u16* __restrict__ bStage,
    int tid, int arow, int brow, int c0, int c1, f32x4 (&acc)[8][4]) {
  bf16x8 a0[4], a1[4], a2[4], a3[4], b0[4], b1[4];
  // ---- phase 0: reads C0 then C1; stage A(S+1) h0 (other buffer)
#pragma unroll
  for (int mi = 0; mi < 4; ++mi)
    a0[mi] = *(const bf16x8*)(lAp + (arow + mi * 16) * 64 + c0);
#pragma unroll
  for (int ni = 0; ni < 4; ++ni)
    b0[ni] = *(const bf16x8*)(lBp + (brow + ni * 16) * 64 + c0);
#pragma unroll
  for (int mi = 0; mi < 4; ++mi)
    a1[mi] = *(const bf16x8*)(lAp + (arow + mi * 16) * 64 + c1);
#pragma unroll
  for (int ni = 0; ni < 4; ++ni)
    b1[ni] = *(const bf16x8*)(lBp + (brow + ni * 16) * 64 + c1);
  if constexpr (SA) stage_half<LDK>(aStage, lAn, tid);
  BAR();
  __builtin_amdgcn_s_setprio(1);
#pragma unroll
  for (int mi = 0; mi < 4; ++mi)
#pragma unroll
    for (int ni = 0; ni < 4; ++ni)
      acc[mi][ni] = __builtin_amdgcn_mfma_f32_16x16x32_bf16(
          a0[mi], b0[ni], acc[mi][ni], 0, 0, 0);
  __builtin_amdgcn_s_setprio(0);
  BAR();
  // ---- phase 1: reads C2; stage A(S+1) h1
#pragma unroll
  for (int mi = 0; mi < 4; ++mi)
    a2[mi] = *(const bf16x8*)(lAp + (arow + 64 + mi * 16) * 64 + c0);
  if constexpr (SA) stage_half<LDK>(aStage + 128 * LDK, lAn + 128 * 64, tid);
  BAR();
  __builtin_amdgcn_s_setprio(1);
#pragma unroll
  for (int mi = 0; mi < 4; ++mi)
#pragma unroll
    for (int ni = 0; ni < 4; ++ni)
      acc[mi][ni] = __builtin_amdgcn_mfma_f32_16x16x32_bf16(
          a1[mi], b1[ni], acc[mi][ni], 0, 0, 0);
  __builtin_amdgcn_s_setprio(0);
  BAR();
  // ---- phase 2: reads C3; stage B(S+2) h0 into lBn (== lBp is only safe
  // because b0/b1 are first-used in ph0/ph1: their loads cannot sink past
  // their first use, so by ph2's barrier all waves' B reads are complete)
#pragma unroll
  for (int mi = 0; mi < 4; ++mi)
    a3[mi] = *(const bf16x8*)(lAp + (arow + 64 + mi * 16) * 64 + c1);
  if constexpr (SB) stage_half<LDK>(bStage, lBn, tid);
  BAR();
  __builtin_amdgcn_s_setprio(1);
#pragma unroll
  for (int mi = 0; mi < 4; ++mi)
#pragma unroll
    for (int ni = 0; ni < 4; ++ni)
      acc[4 + mi][ni] = __builtin_amdgcn_mfma_f32_16x16x32_bf16(
          a2[mi], b0[ni], acc[4 + mi][ni], 0, 0, 0);
  __builtin_amdgcn_s_setprio(0);
  BAR();
  // ---- phase 3: stage B(S+2) h1; counted vmcnt retires A(S+1)+B(S+1)
  if constexpr (SB) stage_half<LDK>(bStage + 128 * LDK, lBn + 128 * 64, tid);
  if constexpr (VM == 4) VMW(4);
  else if constexpr (VM == 0) VMW(0);
  BAR();
  __builtin_amdgcn_s_setprio(1);
#pragma unroll
  for (int mi = 0; mi < 4; ++mi)
#pragma unroll
    for (int ni = 0; ni < 4; ++ni)
      acc[4 + mi][ni] = __builtin_amdgcn_mfma_f32_16x16x32_bf16(
          a3[mi], b1[ni], acc[4 + mi][ni], 0, 0, 0);
  __builtin_amdgcn_s_setprio(0);
  BAR();
}

// ---- 256x256 pipelined GEMM core (gemm1), NK K-tiles of 64 (NK even) --------
template <int NK, int LDK>
__device__ __forceinline__ void gemm_core(const u16* __restrict__ aSrc,
                                          const u16* __restrict__ bSrc, int tid,
                                          u16* lA0, u16* lA1, u16* lB0, u16* lB1,
                                          f32x4 (&acc)[8][4]) {
  const int lane = tid & 63;
  const int wave = tid >> 6;
  const int wm = wave >> 2, wn = wave & 3;
  const int l15 = lane & 15, quad = (lane >> 4) & 3;
  const int arow = wm * 128 + l15;
  const int brow = wn * 64 + l15;
  const int c0 = (quad ^ (l15 & 7)) * 8;
  const int c1 = ((quad + 4) ^ (l15 & 7)) * 8;

  // prologue: K-tile0 (A,B) + B of K-tile1; vmcnt(4) leaves B(1) in flight
  stage_half<LDK>(aSrc, lA0, tid);
  stage_half<LDK>(aSrc + 128 * LDK, lA0 + 128 * 64, tid);
  stage_half<LDK>(bSrc, lB0, tid);
  stage_half<LDK>(bSrc + 128 * LDK, lB0 + 128 * 64, tid);
  stage_half<LDK>(bSrc + 64, lB1, tid);
  stage_half<LDK>(bSrc + 64 + 128 * LDK, lB1 + 128 * 64, tid);
  VMW(4);
  BAR();

#pragma unroll 1
  for (int i = 0; i < NK / 2 - 1; ++i) {
    ktile4<LDK, true, true, 4>(lA0, lB0, lA1, lB0,
                               aSrc + (2 * i + 1) * 64, bSrc + (2 * i + 2) * 64,
                               tid, arow, brow, c0, c1, acc);
    ktile4<LDK, true, true, 4>(lA1, lB1, lA0, lB1,
                               aSrc + (2 * i + 2) * 64, bSrc + (2 * i + 3) * 64,
                               tid, arow, brow, c0, c1, acc);
  }
  ktile4<LDK, true, false, 0>(lA0, lB0, lA1, lB0,
                              aSrc + (NK - 1) * 64, nullptr,
                              tid, arow, brow, c0, c1, acc);
  ktile4<LDK, false, false, -1>(lA1, lB1, lA0, lB1, nullptr, nullptr,
                                tid, arow, brow, c0, c1, acc);
}

// ---- gemm2 K-tile: 128(M)x256(N), 2 phases, triple-buffered, stage 2 ahead --
template <bool ST, int VM>
__device__ __forceinline__ void ktile2(
    const u16* lAp, const u16* lBp, u16* lAs, u16* lBs,
    const u16* __restrict__ aS, const u16* __restrict__ bS,
    int tid, int arow, int brow, int c0, int c1, f32x4 (&acc)[4][4]) {
  bf16x8 a0[4], a1[4], b0[4], b1[4];
  // ---- phase 0: reads C0 (k0) then C1 (k1); stage A(S+2) (distinct buffer)
#pragma unroll
  for (int mi = 0; mi < 4; ++mi)
    a0[mi] = *(const bf16x8*)(lAp + (arow + mi * 16) * 64 + c0);
#pragma unroll
  for (int ni = 0; ni < 4; ++ni)
    b0[ni] = *(const bf16x8*)(lBp + (brow + ni * 16) * 64 + c0);
#pragma unroll
  for (int mi = 0; mi < 4; ++mi)
    a1[mi] = *(const bf16x8*)(lAp + (arow + mi * 16) * 64 + c1);
#pragma unroll
  for (int ni = 0; ni < 4; ++ni)
    b1[ni] = *(const bf16x8*)(lBp + (brow + ni * 16) * 64 + c1);
  if constexpr (ST) stage_half<HN>(aS, lAs, tid);
  BAR();
  __builtin_amdgcn_s_setprio(1);
#pragma unroll
  for (int mi = 0; mi < 4; ++mi)
#pragma unroll
    for (int ni = 0; ni < 4; ++ni)
      acc[mi][ni] = __builtin_amdgcn_mfma_f32_16x16x32_bf16(
          a0[mi], b0[ni], acc[mi][ni], 0, 0, 0);
  __builtin_amdgcn_s_setprio(0);
  BAR();
  // ---- phase 1: stage B(S+2) (distinct buffer); vmcnt(6) retires S+1 loads
  if constexpr (ST) {
    stage_half<HN>(bS, lBs, tid);
    stage_half<HN>(bS + 128 * HN, lBs + 128 * 64, tid);
  }
  if constexpr (VM == 6) VMW(6);
  else if constexpr (VM == 0) VMW(0);
  BAR();
  __builtin_amdgcn_s_setprio(1);
#pragma unroll
  for (int mi = 0; mi < 4; ++mi)
#pragma unroll
    for (int ni = 0; ni < 4; ++ni)
      acc[mi][ni] = __builtin_amdgcn_mfma_f32_16x16x32_bf16(
          a1[mi], b1[ni], acc[mi][ni], 0, 0, 0);
  __builtin_amdgcn_s_setprio(0);
  BAR();
}

// ---- prep kernels ----------------------------------------------------------
__global__ void scales1_kernel(const float* __restrict__ w0,
                               const float* __restrict__ w1,
                               const float* __restrict__ w2,
                               float* __restrict__ partials) {
  __shared__ float red[256];
  const int t = blockIdx.x / 192;      // tensor id
  const int chunk = blockIdx.x % 192;  // 1024-float chunk
  const float* w = (t == 0) ? w0 : (t == 1) ? w1 : w2;
  const float4* w4 = (const float4*)(w + chunk * 1024);
  float4 v = w4[threadIdx.x];
  red[threadIdx.x] = fabsf(v.x) + fabsf(v.y) + fabsf(v.z) + fabsf(v.w);
  __syncthreads();
  for (int off = 128; off; off >>= 1) {
    if (threadIdx.x < off) red[threadIdx.x] += red[threadIdx.x + off];
    __syncthreads();
  }
  if (threadIdx.x == 0) partials[blockIdx.x] = red[0];
}

__global__ void scales2_kernel(const float* __restrict__ partials,
                               float* __restrict__ scales) {
  __shared__ float red[256];
  float s = (threadIdx.x < 192) ? partials[blockIdx.x * 192 + threadIdx.x] : 0.f;
  red[threadIdx.x] = s;
  __syncthreads();
  for (int off = 128; off; off >>= 1) {
    if (threadIdx.x < off) red[threadIdx.x] += red[threadIdx.x + off];
    __syncthreads();
  }
  if (threadIdx.x == 0) scales[blockIdx.x] = red[0] / 196608.f + 1e-8f;
}

// Build Big^T rows ({-1,0,+1} as bf16; absmean scale folded into epilogues).
// ilv 0/1 : gate/up interleaved at 16-col granularity into B_cat [4096 x 768]
// ilv -2  : w_down with k-index permuted by phi (h physical column layout):
//           phi(k) = (k&~31) | ((k&15)<<1) | ((k>>4)&1)
__global__ void build_big_kernel(const float* __restrict__ w,
                                 const float* __restrict__ scales, int sidx,
                                 int A, int B, int ilv, u16* __restrict__ dst) {
  int idx = blockIdx.x * 256 + threadIdx.x;  // n*K8 + k, exact grid
  int K8 = 8 * A;
  int n = idx / K8;
  int k = idx - n * K8;
  int i = k / A, a = k - i * A;
  int c = n / B, b = n - c * B;
  float scale = scales[sidx];
  int j = J_TAB[i * 8 + c];
  float q = rintf(w[(j * A + a) * B + b] / scale);
  q = fminf(1.f, fmaxf(-1.f, q));
  int nd = (ilv >= 0) ? (((n & ~15) << 1) | (ilv << 4) | (n & 15)) : n;
  int kd = (ilv == -2) ? ((k & ~31) | ((k & 15) << 1) | ((k >> 4) & 1)) : k;
  dst[nd * K8 + kd] = f2bf(q * (float)S_TAB[i * 8 + c]);
}

__global__ void cvt_x_kernel(const float* __restrict__ x, u16* __restrict__ xb) {
  int gid = blockIdx.x * 256 + threadIdx.x;  // 8 floats per thread
  const float4* x4 = (const float4*)x;
  float4 v0 = x4[gid * 2], v1 = x4[gid * 2 + 1];
  uint4 o;
  o.x = (u32)f2bf(v0.x) | ((u32)f2bf(v0.y) << 16);
  o.y = (u32)f2bf(v0.z) | ((u32)f2bf(v0.w) << 16);
  o.z = (u32)f2bf(v1.x) | ((u32)f2bf(v1.y) << 16);
  o.w = (u32)f2bf(v1.z) | ((u32)f2bf(v1.w) << 16);
  ((uint4*)xb)[gid] = o;
}

// ---- GEMM1: [M x 768] @ B_cat[4096 x 768]^T -> SiLU(g)*u -> h bf16 [M x 2048]
// h columns stored permuted by phi; epilogue packs (pr0,pr1) into one u32.
__global__ __launch_bounds__(512, 2) void gemm1_kernel(
    const u16* __restrict__ xb, const u16* __restrict__ wgu,
    const float* __restrict__ scales, u16* __restrict__ h) {
  __shared__ __align__(16) u16 lA0[256 * 64], lA1[256 * 64];
  __shared__ __align__(16) u16 lB0[256 * 64], lB1[256 * 64];
  const int tid = threadIdx.x;
  const int logical = (blockIdx.x & 7) * 256 + (blockIdx.x >> 3);
  const int bn = logical & 15;   // 16 N_cat-tiles (fast: A-tile L2 reuse)
  const int bm = logical >> 4;   // 128 M-tiles
  const int m0 = bm * 256, n0 = bn * 256;

  f32x4 acc[8][4] = {};
  gemm_core<12, DK>(xb + (size_t)m0 * DK, wgu + (size_t)n0 * DK, tid,
                    lA0, lA1, lB0, lB1, acc);

  const int lane = tid & 63, wave = tid >> 6;
  const int wm = wave >> 2, wn = wave & 3;
  const int l15 = lane & 15, quad = lane >> 4;
  const float sg = scales[0], su = scales[1];
  const int a_ = bn * 4 + wn;            // 32-col physical group index
  u32* h32 = (u32*)h;
#pragma unroll
  for (int mi = 0; mi < 8; ++mi)
#pragma unroll
    for (int r = 0; r < 4; ++r) {
      int m = m0 + wm * 128 + mi * 16 + quad * 4 + r;
      float g0 = acc[mi][0][r] * sg, u0 = acc[mi][1][r] * su;
      float g1 = acc[mi][2][r] * sg, u1 = acc[mi][3][r] * su;
      float h0 = g0 / (1.f + __expf(-g0)) * u0;
      float h1 = g1 / (1.f + __expf(-g1)) * u1;
      h32[(size_t)m * (HN / 2) + a_ * 16 + l15] =
          (u32)f2bf(h0) | ((u32)f2bf(h1) << 16);
    }
}

// ---- GEMM2: [M x 2048] @ BigD -> out fp32 [M x 768] ------------------------
// 128(M) x 256(N) tile, 768 blocks = 3 exact rounds, triple-buffered pipeline.
__global__ __launch_bounds__(512, 2) void gemm2_kernel(
    const u16* __restrict__ h, const u16* __restrict__ wd,
    const float* __restrict__ scales, float* __restrict__ out) {
  __shared__ __align__(16) u16 lA[3][128 * 64];
  __shared__ __align__(16) u16 lB[3][256 * 64];
  const int tid = threadIdx.x;
  // bijective XCD-chunked swizzle (768 % 8 == 0); bn fastest -> 3 bn of one bm
  // run concurrently and share the h-panel in L2/L3.
  const int logical = (blockIdx.x & 7) * 96 + (blockIdx.x >> 3);
  const int bn = logical % 3;    // 3 N-tiles of 256
  const int bm = logical / 3;    // 256 M-tiles of 128
  const int m0 = bm * 128, n0 = bn * 256;
  const u16* aSrc = h + (size_t)m0 * HN;
  const u16* bSrc = wd + (size_t)n0 * HN;

  const int lane = tid & 63, wave = tid >> 6;
  const int wm = wave >> 2, wn = wave & 3;
  const int l15 = lane & 15, quad = (lane >> 4) & 3;
  const int arow = wm * 64 + l15;
  const int brow = wn * 64 + l15;
  const int c0 = (quad ^ (l15 & 7)) * 8;
  const int c1 = ((quad + 4) ^ (l15 & 7)) * 8;

  f32x4 acc[4][4] = {};

  // prologue: stage ktiles 0 and 1 fully; vmcnt(6) retires ktile 0's 6 loads
  stage_half<HN>(aSrc, lA[0], tid);
  stage_half<HN>(bSrc, lB[0], tid);
  stage_half<HN>(bSrc + 128 * HN, lB[0] + 128 * 64, tid);
  stage_half<HN>(aSrc + 64, lA[1], tid);
  stage_half<HN>(bSrc + 64, lB[1], tid);
  stage_half<HN>(bSrc + 64 + 128 * HN, lB[1] + 128 * 64, tid);
  VMW(6);
  BAR();

  u16 *pA0 = lA[0], *pA1 = lA[1], *pA2 = lA[2];
  u16 *pB0 = lB[0], *pB1 = lB[1], *pB2 = lB[2];
#pragma unroll 1
  for (int S = 0; S < (HN / 64) - 2; ++S) {
    ktile2<true, 6>(pA0, pB0, pA2, pB2,
                    aSrc + (S + 2) * 64, bSrc + (S + 2) * 64,
                    tid, arow, brow, c0, c1, acc);
    u16* tA = pA0; pA0 = pA1; pA1 = pA2; pA2 = tA;
    u16* tB = pB0; pB0 = pB1; pB1 = pB2; pB2 = tB;
  }
  ktile2<false, 0>(pA0, pB0, nullptr, nullptr, nullptr, nullptr,
                   tid, arow, brow, c0, c1, acc);
  ktile2<false, -1>(pA1, pB1, nullptr, nullptr, nullptr, nullptr,
                    tid, arow, brow, c0, c1, acc);

  const float sd = scales[2];
#pragma unroll
  for (int mi = 0; mi < 4; ++mi)
#pragma unroll
    for (int ni = 0; ni < 4; ++ni) {
      const int n = n0 + wn * 64 + ni * 16 + l15;
#pragma unroll
      for (int r = 0; r < 4; ++r) {
        int m = m0 + wm * 64 + mi * 16 + quad * 4 + r;
        out[(size_t)m * DK + n] = acc[mi][ni][r] * sd;
      }
    }
}

// ---- launch ----------------------------------------------------------------
extern "C" void kernel_launch(void* const* d_in, const int* in_sizes, int n_in,
                              void* d_out, int out_size, void* d_ws, size_t ws_size,
                              hipStream_t stream) {
  const float* x      = (const float*)d_in[0];
  const float* w_gate = (const float*)d_in[1];
  const float* w_up   = (const float*)d_in[2];
  const float* w_down = (const float*)d_in[3];
  float* out = (float*)d_out;

  // workspace layout (bytes):
  //  scales[3] @0 | partials[576] @256 | B_cat 6MB @4096 | BigD^T 3MB |
  //  xb 50MB | h 134MB
  char* ws = (char*)d_ws;
  float* scales   = (float*)ws;
  float* partials = (float*)(ws + 256);
  u16* wgu = (u16*)(ws + 4096);
  u16* wd  = (u16*)(ws + 4096 + 6291456u);
  u16* xb  = (u16*)(ws + 4096 + 9437184u);
  u16* h   = (u16*)(ws + 4096 + 9437184u + 50331648u);

  scales1_kernel<<<576, 256, 0, stream>>>(w_gate, w_up, w_down, partials);
  scales2_kernel<<<3, 256, 0, stream>>>(partials, scales);
  build_big_kernel<<<6144, 256, 0, stream>>>(w_gate, scales, 0, 96, 256, 0, wgu);
  build_big_kernel<<<6144, 256, 0, stream>>>(w_up,   scales, 1, 96, 256, 1, wgu);
  build_big_kernel<<<6144, 256, 0, stream>>>(w_down, scales, 2, 256, 96, -2, wd);
  cvt_x_kernel<<<12288, 256, 0, stream>>>(x, xb);
  gemm1_kernel<<<2048, 512, 0, stream>>>(xb, wgu, scales, h);
  gemm2_kernel<<<768, 512, 0, stream>>>(h, wd, scales, out);
}